// Round 7
// baseline (294.226 us; speedup 1.0000x reference)
//
#include <hip/hip_runtime.h>

// GCN fused pipeline. Round 6b: same as round 6 (2-phase double-buffered
// reg-staged pipeline in mfma_tn, split-K 4, stride-68 sC epilogue, NT final
// stores) with the nontemporal-store type fixed (ext_vector f32x4, not HIP
// float4 — the builtin rejects HIP_vector_type).
//
//   K1 gemm_w1t   : [pre|cur]@W1 with fused transpose-bf16 epilogue -> pwT/cwT
//   K2 mfma_tn<3> : z<4: pre1 partials (adj@cwT, fp32 row staging);
//                   z>=4: cur1 partials (adjT@pwT, in-stage transpose)
//   K3 rln        : stacked reduce+leaky+invnorm -> c1,p1, inc1,inp1
//   K4 gemm32     : stacked [c1;p1]@W2 -> [cw2;pw2]
//   K5 gemm32     : stacked brackets   K6 reduce_mcmp   K7 gemm32 EPI3 tails
//   K8 mfma_tn<0> : adj2 = p2n @ c2n^T -> d_out (NT stores)
//
// adj1 (8192x8192 cosine-sim intermediate) is NEVER materialized:
//   adj1 @ cur_w2   = Dp^-1 * pre1 * [ (Dc^-1 cur1)^T @ cur_w2 ]  (128x128)
//   adj1^T @ pre_w2 = Dc^-1 * cur1 * [ (Dp^-1 pre1)^T @ pre_w2 ]  (128x128)

#define NN 8192
#define DD 128

typedef __bf16 bf16x8 __attribute__((ext_vector_type(8)));
typedef float f32x4 __attribute__((ext_vector_type(4)));

static __device__ __forceinline__ float4 ldg4(const float* p) {
    return *reinterpret_cast<const float4*>(p);
}

// Pack 2 floats -> 2 bf16 in a u32 (compiler emits v_cvt_pk_bf16_f32).
static __device__ __forceinline__ unsigned f2bf2(float lo, float hi) {
    __bf16 a = (__bf16)lo, b = (__bf16)hi;
    unsigned short ua = __builtin_bit_cast(unsigned short, a);
    unsigned short ub = __builtin_bit_cast(unsigned short, b);
    return (unsigned)ua | ((unsigned)ub << 16);
}

// compile-time component select of a float4 (j folds in unrolled loops)
#define FCOMP(v, j) ((j) == 0 ? (v).x : (j) == 1 ? (v).y : (j) == 2 ? (v).z : (v).w)

// LDS 16B-slot swizzle: byte_off ^= swz16(row); keeps every staging write and
// fragment read <= 2-way (free) for all access modes here.
static __device__ __forceinline__ int swz16(int row) {
    return (((row & 7) ^ ((row >> 3) & 7)) << 4);
}

// ---------------------------------------------------------------------------
// MFMA GEMM:  C[i,j] (+)= sum_k opA[i,k] * B[k,j],  B given as BT[n][k] bf16.
//   AMODE 0: A bf16 row-major [M][K]       (final GEMM; NT stores)
//   AMODE 3: combined adj pass. z<4: opA = adj (fp32 row-major, bf16-convert
//            in staging), BT = BTa, k-slice z. z>=4: opA = adj^T (fp32,
//            in-stage register transpose), BT = BTb, k-slice z-4.
// Block tile 128x128, BK=64, 4 waves, mfma_f32_16x16x32_bf16.
// Pipeline: double-buffered LDS (2x32KB), reg-staged prefetch depth 1,
// ONE barrier per K-step:
//   loop { LOAD(t+1)->regs ; MFMA(buf[cur]) ; WRITE regs->buf[cur^1] ; bar }
// Epilogue: acc -> sC[128][68] (2-way max) -> coalesced float4 stores.
// ---------------------------------------------------------------------------
template<int AMODE>
__global__ __launch_bounds__(256, 2)
void mfma_tn(const void* __restrict__ Aptr, int lda,
             const unsigned short* __restrict__ BTa,
             const unsigned short* __restrict__ BTb, int ldbt,
             float* __restrict__ C, int ldc,
             int ksplit, int zstride)
{
    __shared__ uint4 smem4[4096];            // 64 KiB: 2 x (sA 16K | sB 16K)
    char* smem = (char*)smem4;

    const int t    = threadIdx.x;
    const int l    = t & 63;
    const int w    = t >> 6;
    const int wr   = (w >> 1) * 64;
    const int wc   = (w & 1) * 64;
    const int lrow = l & 15;
    const int lhi  = l >> 4;
    const int i0   = blockIdx.x * 128;
    const int j0   = blockIdx.y * 128;
    const int z    = blockIdx.z;
    const bool second = (AMODE == 3) && (z >= 4);
    const unsigned short* BT = second ? BTb : BTa;
    const int kbase = (AMODE == 3) ? (z & 3) * ksplit : 0;
    C += (size_t)z * (size_t)zstride;

    const int srow = t >> 3;   // 0..31 (row-major staging)
    const int skg  = t & 7;    // 16B slot along k
    const int u    = t & 31;   // AMODE3-second: col group
    const int r8   = t >> 5;   // AMODE3-second: k-octet

    f32x4 acc[4][4];
    #pragma unroll
    for (int r = 0; r < 4; ++r)
        #pragma unroll
        for (int q = 0; q < 4; ++q)
            #pragma unroll
            for (int e = 0; e < 4; ++e) acc[r][q][e] = 0.0f;

    // staging registers (per-AMODE subset used; rest DCE'd)
    float4 fa[8];
    uint4  ua[4];
    uint4  ub[4];

    auto LOAD = [&](int kk) {
        if (AMODE == 3 && second) {
            const float* gA = (const float*)Aptr;
            #pragma unroll
            for (int e = 0; e < 8; ++e)
                fa[e] = ldg4(&gA[(size_t)(kk + r8 * 8 + e) * lda + i0 + u * 4]);
        } else if (AMODE == 3) {
            #pragma unroll
            for (int it = 0; it < 4; ++it) {
                const float* g = (const float*)Aptr + (size_t)(i0 + it * 32 + srow) * lda + kk + skg * 8;
                fa[2 * it]     = ldg4(g);
                fa[2 * it + 1] = ldg4(g + 4);
            }
        } else {
            #pragma unroll
            for (int it = 0; it < 4; ++it) {
                const unsigned short* g = (const unsigned short*)Aptr + (size_t)(i0 + it * 32 + srow) * lda + kk + skg * 8;
                ua[it] = *reinterpret_cast<const uint4*>(g);
            }
        }
        #pragma unroll
        for (int it = 0; it < 4; ++it) {
            const unsigned short* gb = BT + (size_t)(j0 + it * 32 + srow) * ldbt + kk + skg * 8;
            ub[it] = *reinterpret_cast<const uint4*>(gb);
        }
    };

    auto WRITE = [&](int buf) {
        char* smA = smem + buf * 32768;
        char* smB = smA + 16384;
        if (AMODE == 3 && second) {
            #pragma unroll
            for (int j = 0; j < 4; ++j) {
                const int c = u * 4 + j;
                uint4 wv;
                wv.x = f2bf2(FCOMP(fa[0], j), FCOMP(fa[1], j));
                wv.y = f2bf2(FCOMP(fa[2], j), FCOMP(fa[3], j));
                wv.z = f2bf2(FCOMP(fa[4], j), FCOMP(fa[5], j));
                wv.w = f2bf2(FCOMP(fa[6], j), FCOMP(fa[7], j));
                *reinterpret_cast<uint4*>(smA + c * 128 + ((r8 << 4) ^ swz16(c))) = wv;
            }
        } else if (AMODE == 3) {
            #pragma unroll
            for (int it = 0; it < 4; ++it) {
                const int row = it * 32 + srow;
                uint4 wv;
                wv.x = f2bf2(fa[2 * it].x, fa[2 * it].y);
                wv.y = f2bf2(fa[2 * it].z, fa[2 * it].w);
                wv.z = f2bf2(fa[2 * it + 1].x, fa[2 * it + 1].y);
                wv.w = f2bf2(fa[2 * it + 1].z, fa[2 * it + 1].w);
                *reinterpret_cast<uint4*>(smA + row * 128 + ((skg << 4) ^ swz16(row))) = wv;
            }
        } else {
            #pragma unroll
            for (int it = 0; it < 4; ++it) {
                const int row = it * 32 + srow;
                *reinterpret_cast<uint4*>(smA + row * 128 + ((skg << 4) ^ swz16(row))) = ua[it];
            }
        }
        #pragma unroll
        for (int it = 0; it < 4; ++it) {
            const int row = it * 32 + srow;
            *reinterpret_cast<uint4*>(smB + row * 128 + ((skg << 4) ^ swz16(row))) = ub[it];
        }
    };

    auto MFMA_STEP = [&](int buf) {
        char* smA = smem + buf * 32768;
        char* smB = smA + 16384;
        #pragma unroll
        for (int s = 0; s < 2; ++s) {
            bf16x8 af[4], bq[4];
            #pragma unroll
            for (int r = 0; r < 4; ++r) {
                const int row = wr + r * 16 + lrow;
                af[r] = *reinterpret_cast<const bf16x8*>(
                    smA + row * 128 + ((s * 64 + lhi * 16) ^ swz16(row)));
            }
            #pragma unroll
            for (int q = 0; q < 4; ++q) {
                const int col = wc + q * 16 + lrow;
                bq[q] = *reinterpret_cast<const bf16x8*>(
                    smB + col * 128 + ((s * 64 + lhi * 16) ^ swz16(col)));
            }
            #pragma unroll
            for (int r = 0; r < 4; ++r)
                #pragma unroll
                for (int q = 0; q < 4; ++q)
                    acc[r][q] = __builtin_amdgcn_mfma_f32_16x16x32_bf16(af[r], bq[q], acc[r][q], 0, 0, 0);
        }
    };

    // ---- pipelined main loop: prefetch depth 1, one barrier per K-step ----
    const int nt = ksplit >> 6;
    LOAD(kbase);
    WRITE(0);
    __syncthreads();
    for (int tt = 0; tt < nt; ++tt) {
        const int cur = tt & 1;
        if (tt + 1 < nt) LOAD(kbase + (tt + 1) * 64);
        MFMA_STEP(cur);
        if (tt + 1 < nt) WRITE(cur ^ 1);
        __syncthreads();
    }

    // ---- epilogue: sC[128][68] roundtrip -> coalesced float4 stores ----
    float* sC = (float*)smem;
    #pragma unroll
    for (int h = 0; h < 2; ++h) {
        if ((w & 1) == h) {
            #pragma unroll
            for (int r = 0; r < 4; ++r)
                #pragma unroll
                for (int q = 0; q < 4; ++q)
                    #pragma unroll
                    for (int i = 0; i < 4; ++i)
                        sC[(wr + r * 16 + lhi * 4 + i) * 68 + q * 16 + lrow] = acc[r][q][i];
        }
        __syncthreads();
        #pragma unroll
        for (int it = 0; it < 8; ++it) {
            const int idx = it * 256 + t;
            const int row = idx >> 4;
            const int c4  = (idx & 15) << 2;
            f32x4 v = *reinterpret_cast<const f32x4*>(&sC[row * 68 + c4]);
            float* dst = &C[(size_t)(i0 + row) * ldc + j0 + h * 64 + c4];
            if constexpr (AMODE == 0)
                __builtin_nontemporal_store(v, reinterpret_cast<f32x4*>(dst));
            else
                *reinterpret_cast<f32x4*>(dst) = v;
        }
        __syncthreads();
    }
}

// ---------------------------------------------------------------------------
// K1: [pre|cur] @ W1 with fused transpose-bf16 epilogue.
// blockIdx.x < 256 -> pre rows -> pwT ; >= 256 -> cur rows -> cwT.
// ---------------------------------------------------------------------------
__global__ __launch_bounds__(256, 2)
void gemm_w1t(const float* __restrict__ pre, const float* __restrict__ cur,
              const float* __restrict__ W1,
              unsigned short* __restrict__ pwT, unsigned short* __restrict__ cwT)
{
    __shared__ float sA[32][68];
    __shared__ float sB[64][128];            // reused as sC[32][128]

    const int t  = threadIdx.x;
    const int ct = t & 31;
    const int rt = t >> 5;
    const int bx = blockIdx.x;
    const bool isCur = bx >= 256;
    const float* A = isCur ? cur : pre;
    unsigned short* XT = isCur ? cwT : pwT;
    const int i0 = (bx & 255) * 32;

    float4 acc[4];
    #pragma unroll
    for (int r = 0; r < 4; ++r) { acc[r].x = 0.f; acc[r].y = 0.f; acc[r].z = 0.f; acc[r].w = 0.f; }

    for (int k0 = 0; k0 < DD; k0 += 64) {
        #pragma unroll
        for (int f = 0; f < 2; ++f) {
            const int row = (t >> 4) + 16 * f;
            const int kk4 = (t & 15) << 2;
            *reinterpret_cast<float4*>(&sA[row][kk4]) =
                ldg4(&A[(size_t)(i0 + row) * DD + k0 + kk4]);
        }
        #pragma unroll
        for (int f = 0; f < 8; ++f) {
            const int idx = f * 256 + t;
            const int kk  = idx >> 5;
            const int c4  = (idx & 31) << 2;
            *reinterpret_cast<float4*>(&sB[kk][c4]) =
                ldg4(&W1[(size_t)(k0 + kk) * DD + c4]);
        }
        __syncthreads();
        #pragma unroll 4
        for (int kk = 0; kk < 64; kk += 4) {
            float4 a[4], b[4];
            #pragma unroll
            for (int r = 0; r < 4; ++r)
                a[r] = *reinterpret_cast<const float4*>(&sA[rt * 4 + r][kk]);
            #pragma unroll
            for (int q = 0; q < 4; ++q)
                b[q] = *reinterpret_cast<const float4*>(&sB[kk + q][ct * 4]);
            #pragma unroll
            for (int r = 0; r < 4; ++r) {
                acc[r].x += a[r].x * b[0].x; acc[r].y += a[r].x * b[0].y;
                acc[r].z += a[r].x * b[0].z; acc[r].w += a[r].x * b[0].w;
                acc[r].x += a[r].y * b[1].x; acc[r].y += a[r].y * b[1].y;
                acc[r].z += a[r].y * b[1].z; acc[r].w += a[r].y * b[1].w;
                acc[r].x += a[r].z * b[2].x; acc[r].y += a[r].z * b[2].y;
                acc[r].z += a[r].z * b[2].z; acc[r].w += a[r].z * b[2].w;
                acc[r].x += a[r].w * b[3].x; acc[r].y += a[r].w * b[3].y;
                acc[r].z += a[r].w * b[3].z; acc[r].w += a[r].w * b[3].w;
            }
        }
        __syncthreads();
    }

    // Transpose epilogue: acc -> sC[32][128] f32 -> bf16 XT[n][i0..i0+31]
    float* sC = &sB[0][0];
    #pragma unroll
    for (int r = 0; r < 4; ++r)
        *reinterpret_cast<float4*>(&sC[(rt * 4 + r) * 128 + ct * 4]) = acc[r];
    __syncthreads();

    const int n = t & 127;
    const int g = t >> 7;
    #pragma unroll
    for (int c = 0; c < 2; ++c) {
        const int ii = (2 * g + c) * 8;
        uint4 wv;
        wv.x = f2bf2(sC[(ii + 0) * 128 + n], sC[(ii + 1) * 128 + n]);
        wv.y = f2bf2(sC[(ii + 2) * 128 + n], sC[(ii + 3) * 128 + n]);
        wv.z = f2bf2(sC[(ii + 4) * 128 + n], sC[(ii + 5) * 128 + n]);
        wv.w = f2bf2(sC[(ii + 6) * 128 + n], sC[(ii + 7) * 128 + n]);
        *reinterpret_cast<uint4*>(&XT[(size_t)n * NN + i0 + ii]) = wv;
    }
}

// ---------------------------------------------------------------------------
// K3: stacked split-K reduce + leaky ReLU + inverse row norm.
// blockIdx.y = 0 -> c1 (kparts slots 4..7), 1 -> p1 (slots 0..3).
// ---------------------------------------------------------------------------
__global__ __launch_bounds__(128)
void rln(const float* __restrict__ kparts, float* __restrict__ Xbase,
         float* __restrict__ invbase)
{
    const int i = blockIdx.x;
    const int y = blockIdx.y;
    const int t = threadIdx.x;
    const float* part = kparts + (size_t)(1 - y) * 4 * (NN * DD);
    float* X = Xbase + (size_t)y * (NN * DD);
    float* inv_n = invbase + y * NN;

    float s = 0.f;
    #pragma unroll
    for (int z = 0; z < 4; ++z)
        s += part[(size_t)z * (NN * DD) + (size_t)i * DD + t];
    float y_ = (s >= 0.f) ? s : 0.01f * s;
    X[(size_t)i * DD + t] = y_;
    float n = y_ * y_;
    #pragma unroll
    for (int o = 32; o > 0; o >>= 1) n += __shfl_down(n, o);
    __shared__ float p[2];
    if ((t & 63) == 0) p[t >> 6] = n;
    __syncthreads();
    if (t == 0) inv_n[i] = 1.0f / sqrtf(p[0] + p[1]);
}

// ---------------------------------------------------------------------------
// fp32 tiled GEMM, N=128 fixed (j0=0); blockIdx.y = side with element strides
// ystA/ystB/ystC/ystS; blockIdx.z = split-K slice (C += z*zstride, EPI0).
//   EPI 0: raw fp32 store to C
//   EPI 3: y=leaky(acc*rscale[row]); row-norm via 32-lane shfl; bf16 to Cb.
//   SCALEK (with TRANSA): A *= kscale[k] during staging.
// ---------------------------------------------------------------------------
template<bool TRANSA, bool SCALEK, int EPI>
__global__ __launch_bounds__(256, 2)
void gemm32(const float* __restrict__ A, int lda,
            const float* __restrict__ B, int ldb,
            float* __restrict__ C, unsigned short* __restrict__ Cb,
            int ksplit_len, int zstride,
            const float* __restrict__ kscale,
            const float* __restrict__ rscale,
            int ystA, int ystB, int ystC, int ystS)
{
    __shared__ float sA[32][68];
    __shared__ float sB[64][128];

    const int t  = threadIdx.x;
    const int ct = t & 31;
    const int rt = t >> 5;
    const int i0 = blockIdx.x * 32;
    const int side = blockIdx.y;
    const int kgbase = blockIdx.z * ksplit_len;

    A += (ptrdiff_t)side * ystA;
    B += (ptrdiff_t)side * ystB;
    if constexpr (EPI == 0)
        C += (ptrdiff_t)side * ystC + (size_t)blockIdx.z * (size_t)zstride;
    if constexpr (EPI == 3)
        Cb += (ptrdiff_t)side * ystC;
    if constexpr (SCALEK) kscale += (ptrdiff_t)side * ystS;
    if constexpr (EPI == 3) rscale += (ptrdiff_t)side * ystS;

    float4 acc[4];
    #pragma unroll
    for (int r = 0; r < 4; ++r) { acc[r].x = 0.f; acc[r].y = 0.f; acc[r].z = 0.f; acc[r].w = 0.f; }

    for (int k0 = 0; k0 < ksplit_len; k0 += 64) {
        const int kg = kgbase + k0;
        if (!TRANSA) {
            #pragma unroll
            for (int f = 0; f < 2; ++f) {
                const int row = (t >> 4) + 16 * f;
                const int kk4 = (t & 15) << 2;
                *reinterpret_cast<float4*>(&sA[row][kk4]) =
                    ldg4(&A[(size_t)(i0 + row) * lda + kg + kk4]);
            }
        } else {
            #pragma unroll
            for (int f = 0; f < 2; ++f) {
                const int kk = (t >> 3) + 32 * f;
                const int r4 = (t & 7) << 2;
                float4 v = ldg4(&A[(size_t)(kg + kk) * lda + i0 + r4]);
                if (SCALEK) {
                    const float s = kscale[kg + kk];
                    v.x *= s; v.y *= s; v.z *= s; v.w *= s;
                }
                sA[r4 + 0][kk] = v.x; sA[r4 + 1][kk] = v.y;
                sA[r4 + 2][kk] = v.z; sA[r4 + 3][kk] = v.w;
            }
        }
        #pragma unroll
        for (int f = 0; f < 8; ++f) {
            const int idx = f * 256 + t;
            const int kk  = idx >> 5;
            const int c4  = (idx & 31) << 2;
            *reinterpret_cast<float4*>(&sB[kk][c4]) =
                ldg4(&B[(size_t)(kg + kk) * ldb + c4]);
        }
        __syncthreads();
        #pragma unroll 4
        for (int kk = 0; kk < 64; kk += 4) {
            float4 a[4], b[4];
            #pragma unroll
            for (int r = 0; r < 4; ++r)
                a[r] = *reinterpret_cast<const float4*>(&sA[rt * 4 + r][kk]);
            #pragma unroll
            for (int q = 0; q < 4; ++q)
                b[q] = *reinterpret_cast<const float4*>(&sB[kk + q][ct * 4]);
            #pragma unroll
            for (int r = 0; r < 4; ++r) {
                acc[r].x += a[r].x * b[0].x; acc[r].y += a[r].x * b[0].y;
                acc[r].z += a[r].x * b[0].z; acc[r].w += a[r].x * b[0].w;
                acc[r].x += a[r].y * b[1].x; acc[r].y += a[r].y * b[1].y;
                acc[r].z += a[r].y * b[1].z; acc[r].w += a[r].y * b[1].w;
                acc[r].x += a[r].z * b[2].x; acc[r].y += a[r].z * b[2].y;
                acc[r].z += a[r].z * b[2].z; acc[r].w += a[r].z * b[2].w;
                acc[r].x += a[r].w * b[3].x; acc[r].y += a[r].w * b[3].y;
                acc[r].z += a[r].w * b[3].z; acc[r].w += a[r].w * b[3].w;
            }
        }
        __syncthreads();
    }

    #pragma unroll
    for (int r = 0; r < 4; ++r) {
        const int rg = i0 + rt * 4 + r;
        if constexpr (EPI == 3) {
            const float s = rscale[rg];
            float y0 = acc[r].x * s, y1 = acc[r].y * s,
                  y2 = acc[r].z * s, y3 = acc[r].w * s;
            y0 = (y0 >= 0.f) ? y0 : 0.01f * y0;
            y1 = (y1 >= 0.f) ? y1 : 0.01f * y1;
            y2 = (y2 >= 0.f) ? y2 : 0.01f * y2;
            y3 = (y3 >= 0.f) ? y3 : 0.01f * y3;
            float ss = y0 * y0 + y1 * y1 + y2 * y2 + y3 * y3;
            #pragma unroll
            for (int m = 16; m > 0; m >>= 1) ss += __shfl_xor(ss, m);
            const float invn = rsqrtf(ss);
            uint2 wv;
            wv.x = f2bf2(y0 * invn, y1 * invn);
            wv.y = f2bf2(y2 * invn, y3 * invn);
            *reinterpret_cast<uint2*>(&Cb[(size_t)rg * DD + ct * 4]) = wv;
        } else {
            *reinterpret_cast<float4*>(&C[(size_t)rg * DD + ct * 4]) = acc[r];
        }
    }
}

// ---------------------------------------------------------------------------
// K6: stacked reduce for the brackets: out[y][i] = sum_z part[y][z][i].
// ---------------------------------------------------------------------------
__global__ __launch_bounds__(256)
void reduce_mcmp(const float* __restrict__ part, float* __restrict__ out)
{
    const int y = blockIdx.y;
    const int i = blockIdx.x * 256 + threadIdx.x;   // 0..16383
    part += (size_t)y * 32 * 16384;
    out  += (size_t)y * 16384;
    float a = 0.f;
    #pragma unroll
    for (int z = 0; z < 32; ++z) a += part[(size_t)z * 16384 + i];
    out[i] = a;
}

// ---------------------------------------------------------------------------
extern "C" void kernel_launch(void* const* d_in, const int* in_sizes, int n_in,
                              void* d_out, int out_size, void* d_ws, size_t ws_size,
                              hipStream_t stream)
{
    const float* pre = (const float*)d_in[0];
    const float* cur = (const float*)d_in[1];
    const float* adj = (const float*)d_in[2];
    const float* W1  = (const float*)d_in[3];
    const float* W2  = (const float*)d_in[4];
    float* out = (float*)d_out;
    float* ws  = (float*)d_ws;

    const size_t M1 = (size_t)NN * DD;   // 1,048,576

    // ws layout (~64 MB of 1 GiB); d_out untouched until K8.
    float* cwpw2 = ws + 0 * M1;                               // [cw2; pw2] 2*M1
    float* c1    = ws + 2 * M1;                               // c1 then p1 (contig)
    unsigned short* c2n_b = (unsigned short*)(ws + 4 * M1);   // c2n then p2n (bf16)
    unsigned short* p2n_b = c2n_b + M1;
    unsigned short* cwT_b = (unsigned short*)(ws + 5 * M1);   // [128][8192] bf16
    unsigned short* pwT_b = cwT_b + M1;
    float* bparts = ws + 6 * M1;                              // [2][32][16384]
    float* mcmp   = ws + 7 * M1;                              // [mc; mp] 32768
    float* inc1   = mcmp + 32768;                             // inc1 then inp1
    float* kparts = ws + 8 * M1;                              // [8][M1]

    // K1: [pre|cur]@W1 -> pwT_b / cwT_b (transposed bf16, no fp32 store)
    gemm_w1t<<<dim3(512,1,1),256,0,stream>>>(pre, cur, W1, pwT_b, cwT_b);

    // K2: combined adj pass, split-K 4 per side (512 blocks = 2/CU resident).
    //     z<4: pre1 partials (adj@cwT) -> kparts[0..3];
    //     z>=4: cur1 partials (adjT@pwT) -> kparts[4..7].
    mfma_tn<3><<<dim3(64,1,8),256,0,stream>>>(adj, NN, cwT_b, pwT_b, NN,
                                              kparts, DD, NN/4, (int)M1);

    // K3: stacked reduce+leaky+invnorm: y=0 -> c1/inc1, y=1 -> p1/inp1
    rln<<<dim3(NN,2,1),128,0,stream>>>(kparts, c1, inc1);

    // K4: [c1;p1]@W2 -> [cw2;pw2] (single M=16384 GEMM)
    gemm32<false,false,0><<<dim3(512,1,1),256,0,stream>>>(
        c1, DD, W2, DD, cwpw2, (unsigned short*)nullptr,
        DD, 0, nullptr, nullptr, 0,0,0,0);

    // K5: stacked brackets: side0 mc = (Dc^-1 c1)^T@cw2, side1 mp = (Dp^-1 p1)^T@pw2
    gemm32<true,true,0><<<dim3(4,2,32),256,0,stream>>>(
        c1, DD, cwpw2, DD, bparts, (unsigned short*)nullptr,
        256, 16384, inc1, nullptr,
        (int)M1, (int)M1, 32*16384, NN);

    // K6: stacked split-K reduce -> mcmp = [mc; mp]
    reduce_mcmp<<<dim3(64,2,1),256,0,stream>>>(bparts, mcmp);

    // K7: stacked fused tails (EPI3):
    //   side0: c2n = normrows(leaky(Dc^-1 c1 @ mp)) ; side1: p2n = ... (mc)
    gemm32<false,false,3><<<dim3(256,2,1),256,0,stream>>>(
        c1, DD, mcmp + 16384, DD, (float*)nullptr, c2n_b,
        DD, 0, nullptr, inc1,
        (int)M1, -16384, (int)M1, NN);

    // K8: adj2 = p2n @ c2n^T -> d_out (NT stores)
    mfma_tn<0><<<dim3(64,64,1),256,0,stream>>>(p2n_b, DD, c2n_b, c2n_b, DD,
                                               out, NN, DD, 0);
}

// Round 8
// 284.593 us; speedup vs baseline: 1.0338x; 1.0338x over previous
//
#include <hip/hip_runtime.h>

// GCN fused pipeline. Round 8: revert the reg-pipeline (measured neutral),
// maximize residency instead: single 34.8KB LDS buffer (4 blocks/CU),
// launch_bounds(256,4), split-K 16 on the adj pass (1024 blocks = 4/CU),
// stride-68 sC epilogue (2-way = free), NT stores for the final 268 MB.
//
//   K1 gemm_w1t   : [pre|cur]@W1 with fused transpose-bf16 epilogue -> pwT/cwT
//   K2 mfma_tn<3> : z<8: pre1 partials (adj@cwT, fp32 row staging);
//                   z>=8: cur1 partials (adjT@pwT, in-stage transpose)
//   K3 rln        : stacked reduce+leaky+invnorm -> c1,p1, inc1,inp1
//   K4 gemm32     : stacked [c1;p1]@W2 -> [cw2;pw2]
//   K5 gemm32     : stacked brackets   K6 reduce_mcmp   K7 gemm32 EPI3 tails
//   K8 mfma_tn<0> : adj2 = p2n @ c2n^T -> d_out (NT stores)
//
// adj1 (8192x8192 cosine-sim intermediate) is NEVER materialized:
//   adj1 @ cur_w2   = Dp^-1 * pre1 * [ (Dc^-1 cur1)^T @ cur_w2 ]  (128x128)
//   adj1^T @ pre_w2 = Dc^-1 * cur1 * [ (Dp^-1 pre1)^T @ pre_w2 ]  (128x128)

#define NN 8192
#define DD 128

typedef __bf16 bf16x8 __attribute__((ext_vector_type(8)));
typedef float f32x4 __attribute__((ext_vector_type(4)));

static __device__ __forceinline__ float4 ldg4(const float* p) {
    return *reinterpret_cast<const float4*>(p);
}

// Pack 2 floats -> 2 bf16 in a u32 (compiler emits v_cvt_pk_bf16_f32).
static __device__ __forceinline__ unsigned f2bf2(float lo, float hi) {
    __bf16 a = (__bf16)lo, b = (__bf16)hi;
    unsigned short ua = __builtin_bit_cast(unsigned short, a);
    unsigned short ub = __builtin_bit_cast(unsigned short, b);
    return (unsigned)ua | ((unsigned)ub << 16);
}

// LDS 16B-slot swizzle: byte_off ^= swz16(row); keeps every staging write and
// fragment read <= 2-way (free) for all access modes here.
static __device__ __forceinline__ int swz16(int row) {
    return (((row & 7) ^ ((row >> 3) & 7)) << 4);
}

// ---------------------------------------------------------------------------
// MFMA GEMM:  C[i,j] (+)= sum_k opA[i,k] * B[k,j],  B given as BT[n][k] bf16.
//   AMODE 0: A bf16 row-major [M][K]       (final GEMM; NT stores)
//   AMODE 3: combined adj pass. z<8: opA = adj (fp32 row-major, bf16-convert
//            in staging), BT = BTa, k-slice z. z>=8: opA = adj^T (fp32,
//            in-stage register transpose), BT = BTb, k-slice z-8.
// Block tile 128x128, BK=64, 4 waves, mfma_f32_16x16x32_bf16.
// Single 32KB stage buffer, 2 barriers/K-step — inter-block overlap (4/CU)
// does the latency hiding (R6's reg-pipeline measured neutral; reverted).
// Epilogue: acc -> sC[128][68] (2-way = free) -> coalesced float4 stores.
// ---------------------------------------------------------------------------
template<int AMODE>
__global__ __launch_bounds__(256, 4)
void mfma_tn(const void* __restrict__ Aptr, int lda,
             const unsigned short* __restrict__ BTa,
             const unsigned short* __restrict__ BTb, int ldbt,
             float* __restrict__ C, int ldc,
             int ksplit, int zstride)
{
    __shared__ alignas(16) char smem[34816];   // 16K sA | 16K sB; sC overlays
    char* smA = smem;
    char* smB = smem + 16384;

    const int t    = threadIdx.x;
    const int l    = t & 63;
    const int w    = t >> 6;
    const int wr   = (w >> 1) * 64;
    const int wc   = (w & 1) * 64;
    const int lrow = l & 15;
    const int lhi  = l >> 4;
    const int i0   = blockIdx.x * 128;
    const int j0   = blockIdx.y * 128;
    const int z    = blockIdx.z;
    const bool second = (AMODE == 3) && (z >= 8);
    const unsigned short* BT = second ? BTb : BTa;
    const int kbase = (AMODE == 3) ? (z & 7) * ksplit : 0;
    C += (size_t)z * (size_t)zstride;

    const int srow = t >> 3;   // 0..31 (row-major staging)
    const int skg  = t & 7;    // 16B slot along k
    const int u    = t & 31;   // AMODE3-second: col group
    const int r8   = t >> 5;   // AMODE3-second: k-octet

    f32x4 acc[4][4];
    #pragma unroll
    for (int r = 0; r < 4; ++r)
        #pragma unroll
        for (int q = 0; q < 4; ++q)
            #pragma unroll
            for (int e = 0; e < 4; ++e) acc[r][q][e] = 0.0f;

    for (int k0 = 0; k0 < ksplit; k0 += 64) {
        const int kk = kbase + k0;

        // ---- stage A ----
        if (AMODE == 3 && second) {
            // adj^T: thread owns adj rows [kk+r8*8,+8) x cols [i0+4u,+4).
            // 8 float4 loads (1KB/instr coalesced), register transpose,
            // 4x ds_write_b128.
            const float* gA = (const float*)Aptr;
            float4 rv[8];
            #pragma unroll
            for (int e = 0; e < 8; ++e)
                rv[e] = ldg4(&gA[(size_t)(kk + r8 * 8 + e) * lda + i0 + u * 4]);
            {
                int c = u * 4;
                uint4 wv;
                wv.x = f2bf2(rv[0].x, rv[1].x); wv.y = f2bf2(rv[2].x, rv[3].x);
                wv.z = f2bf2(rv[4].x, rv[5].x); wv.w = f2bf2(rv[6].x, rv[7].x);
                *reinterpret_cast<uint4*>(smA + c * 128 + ((r8 << 4) ^ swz16(c))) = wv;
                c = u * 4 + 1;
                wv.x = f2bf2(rv[0].y, rv[1].y); wv.y = f2bf2(rv[2].y, rv[3].y);
                wv.z = f2bf2(rv[4].y, rv[5].y); wv.w = f2bf2(rv[6].y, rv[7].y);
                *reinterpret_cast<uint4*>(smA + c * 128 + ((r8 << 4) ^ swz16(c))) = wv;
                c = u * 4 + 2;
                wv.x = f2bf2(rv[0].z, rv[1].z); wv.y = f2bf2(rv[2].z, rv[3].z);
                wv.z = f2bf2(rv[4].z, rv[5].z); wv.w = f2bf2(rv[6].z, rv[7].z);
                *reinterpret_cast<uint4*>(smA + c * 128 + ((r8 << 4) ^ swz16(c))) = wv;
                c = u * 4 + 3;
                wv.x = f2bf2(rv[0].w, rv[1].w); wv.y = f2bf2(rv[2].w, rv[3].w);
                wv.z = f2bf2(rv[4].w, rv[5].w); wv.w = f2bf2(rv[6].w, rv[7].w);
                *reinterpret_cast<uint4*>(smA + c * 128 + ((r8 << 4) ^ swz16(c))) = wv;
            }
        } else {
            #pragma unroll
            for (int it = 0; it < 4; ++it) {
                const int row = it * 32 + srow;
                const int dst = row * 128 + ((skg << 4) ^ swz16(row));
                if constexpr (AMODE == 3) {
                    const float* g = (const float*)Aptr + (size_t)(i0 + row) * lda + kk + skg * 8;
                    float4 f0 = ldg4(g), f1 = ldg4(g + 4);
                    uint4 wv;
                    wv.x = f2bf2(f0.x, f0.y);
                    wv.y = f2bf2(f0.z, f0.w);
                    wv.z = f2bf2(f1.x, f1.y);
                    wv.w = f2bf2(f1.z, f1.w);
                    *reinterpret_cast<uint4*>(smA + dst) = wv;
                } else {
                    const unsigned short* g = (const unsigned short*)Aptr + (size_t)(i0 + row) * lda + kk + skg * 8;
                    *reinterpret_cast<uint4*>(smA + dst) = *reinterpret_cast<const uint4*>(g);
                }
            }
        }

        // ---- stage B (BT row-major) ----
        #pragma unroll
        for (int it = 0; it < 4; ++it) {
            const int row = it * 32 + srow;
            const int dst = row * 128 + ((skg << 4) ^ swz16(row));
            const unsigned short* gb = BT + (size_t)(j0 + it * 32 + srow) * ldbt + kk + skg * 8;
            *reinterpret_cast<uint4*>(smB + dst) = *reinterpret_cast<const uint4*>(gb);
        }
        __syncthreads();

        // ---- MFMA ----
        #pragma unroll
        for (int s = 0; s < 2; ++s) {
            bf16x8 af[4], bq[4];
            #pragma unroll
            for (int r = 0; r < 4; ++r) {
                const int row = wr + r * 16 + lrow;
                af[r] = *reinterpret_cast<const bf16x8*>(
                    smA + row * 128 + ((s * 64 + lhi * 16) ^ swz16(row)));
            }
            #pragma unroll
            for (int q = 0; q < 4; ++q) {
                const int col = wc + q * 16 + lrow;
                bq[q] = *reinterpret_cast<const bf16x8*>(
                    smB + col * 128 + ((s * 64 + lhi * 16) ^ swz16(col)));
            }
            #pragma unroll
            for (int r = 0; r < 4; ++r)
                #pragma unroll
                for (int q = 0; q < 4; ++q)
                    acc[r][q] = __builtin_amdgcn_mfma_f32_16x16x32_bf16(af[r], bq[q], acc[r][q], 0, 0, 0);
        }
        __syncthreads();
    }

    // ---- epilogue: sC[128][68] roundtrip -> coalesced float4 stores ----
    float* sC = (float*)smem;
    #pragma unroll
    for (int h = 0; h < 2; ++h) {
        if ((w & 1) == h) {
            #pragma unroll
            for (int r = 0; r < 4; ++r)
                #pragma unroll
                for (int q = 0; q < 4; ++q)
                    #pragma unroll
                    for (int i = 0; i < 4; ++i)
                        sC[(wr + r * 16 + lhi * 4 + i) * 68 + q * 16 + lrow] = acc[r][q][i];
        }
        __syncthreads();
        #pragma unroll
        for (int it = 0; it < 8; ++it) {
            const int idx = it * 256 + t;
            const int row = idx >> 4;
            const int c4  = (idx & 15) << 2;
            f32x4 v = *reinterpret_cast<const f32x4*>(&sC[row * 68 + c4]);
            float* dst = &C[(size_t)(i0 + row) * ldc + j0 + h * 64 + c4];
            if constexpr (AMODE == 0)
                __builtin_nontemporal_store(v, reinterpret_cast<f32x4*>(dst));
            else
                *reinterpret_cast<f32x4*>(dst) = v;
        }
        __syncthreads();
    }
}

// ---------------------------------------------------------------------------
// K1: [pre|cur] @ W1 with fused transpose-bf16 epilogue.
// blockIdx.x < 256 -> pre rows -> pwT ; >= 256 -> cur rows -> cwT.
// ---------------------------------------------------------------------------
__global__ __launch_bounds__(256, 2)
void gemm_w1t(const float* __restrict__ pre, const float* __restrict__ cur,
              const float* __restrict__ W1,
              unsigned short* __restrict__ pwT, unsigned short* __restrict__ cwT)
{
    __shared__ float sA[32][68];
    __shared__ float sB[64][128];            // reused as sC[32][128]

    const int t  = threadIdx.x;
    const int ct = t & 31;
    const int rt = t >> 5;
    const int bx = blockIdx.x;
    const bool isCur = bx >= 256;
    const float* A = isCur ? cur : pre;
    unsigned short* XT = isCur ? cwT : pwT;
    const int i0 = (bx & 255) * 32;

    float4 acc[4];
    #pragma unroll
    for (int r = 0; r < 4; ++r) { acc[r].x = 0.f; acc[r].y = 0.f; acc[r].z = 0.f; acc[r].w = 0.f; }

    for (int k0 = 0; k0 < DD; k0 += 64) {
        #pragma unroll
        for (int f = 0; f < 2; ++f) {
            const int row = (t >> 4) + 16 * f;
            const int kk4 = (t & 15) << 2;
            *reinterpret_cast<float4*>(&sA[row][kk4]) =
                ldg4(&A[(size_t)(i0 + row) * DD + k0 + kk4]);
        }
        #pragma unroll
        for (int f = 0; f < 8; ++f) {
            const int idx = f * 256 + t;
            const int kk  = idx >> 5;
            const int c4  = (idx & 31) << 2;
            *reinterpret_cast<float4*>(&sB[kk][c4]) =
                ldg4(&W1[(size_t)(k0 + kk) * DD + c4]);
        }
        __syncthreads();
        #pragma unroll 4
        for (int kk = 0; kk < 64; kk += 4) {
            float4 a[4], b[4];
            #pragma unroll
            for (int r = 0; r < 4; ++r)
                a[r] = *reinterpret_cast<const float4*>(&sA[rt * 4 + r][kk]);
            #pragma unroll
            for (int q = 0; q < 4; ++q)
                b[q] = *reinterpret_cast<const float4*>(&sB[kk + q][ct * 4]);
            #pragma unroll
            for (int r = 0; r < 4; ++r) {
                acc[r].x += a[r].x * b[0].x; acc[r].y += a[r].x * b[0].y;
                acc[r].z += a[r].x * b[0].z; acc[r].w += a[r].x * b[0].w;
                acc[r].x += a[r].y * b[1].x; acc[r].y += a[r].y * b[1].y;
                acc[r].z += a[r].y * b[1].z; acc[r].w += a[r].y * b[1].w;
                acc[r].x += a[r].z * b[2].x; acc[r].y += a[r].z * b[2].y;
                acc[r].z += a[r].z * b[2].z; acc[r].w += a[r].z * b[2].w;
                acc[r].x += a[r].w * b[3].x; acc[r].y += a[r].w * b[3].y;
                acc[r].z += a[r].w * b[3].z; acc[r].w += a[r].w * b[3].w;
            }
        }
        __syncthreads();
    }

    // Transpose epilogue: acc -> sC[32][128] f32 -> bf16 XT[n][i0..i0+31]
    float* sC = &sB[0][0];
    #pragma unroll
    for (int r = 0; r < 4; ++r)
        *reinterpret_cast<float4*>(&sC[(rt * 4 + r) * 128 + ct * 4]) = acc[r];
    __syncthreads();

    const int n = t & 127;
    const int g = t >> 7;
    #pragma unroll
    for (int c = 0; c < 2; ++c) {
        const int ii = (2 * g + c) * 8;
        uint4 wv;
        wv.x = f2bf2(sC[(ii + 0) * 128 + n], sC[(ii + 1) * 128 + n]);
        wv.y = f2bf2(sC[(ii + 2) * 128 + n], sC[(ii + 3) * 128 + n]);
        wv.z = f2bf2(sC[(ii + 4) * 128 + n], sC[(ii + 5) * 128 + n]);
        wv.w = f2bf2(sC[(ii + 6) * 128 + n], sC[(ii + 7) * 128 + n]);
        *reinterpret_cast<uint4*>(&XT[(size_t)n * NN + i0 + ii]) = wv;
    }
}

// ---------------------------------------------------------------------------
// K3: stacked split-K reduce + leaky ReLU + inverse row norm.
// blockIdx.y = 0 -> c1 (kparts slots 8..15), 1 -> p1 (slots 0..7).
// ---------------------------------------------------------------------------
__global__ __launch_bounds__(128)
void rln(const float* __restrict__ kparts, float* __restrict__ Xbase,
         float* __restrict__ invbase)
{
    const int i = blockIdx.x;
    const int y = blockIdx.y;
    const int t = threadIdx.x;
    const float* part = kparts + (size_t)(1 - y) * 8 * (NN * DD);
    float* X = Xbase + (size_t)y * (NN * DD);
    float* inv_n = invbase + y * NN;

    float s = 0.f;
    #pragma unroll
    for (int z = 0; z < 8; ++z)
        s += part[(size_t)z * (NN * DD) + (size_t)i * DD + t];
    float y_ = (s >= 0.f) ? s : 0.01f * s;
    X[(size_t)i * DD + t] = y_;
    float n = y_ * y_;
    #pragma unroll
    for (int o = 32; o > 0; o >>= 1) n += __shfl_down(n, o);
    __shared__ float p[2];
    if ((t & 63) == 0) p[t >> 6] = n;
    __syncthreads();
    if (t == 0) inv_n[i] = 1.0f / sqrtf(p[0] + p[1]);
}

// ---------------------------------------------------------------------------
// fp32 tiled GEMM, N=128 fixed (j0=0); blockIdx.y = side with element strides
// ystA/ystB/ystC/ystS; blockIdx.z = split-K slice (C += z*zstride, EPI0).
//   EPI 0: raw fp32 store to C
//   EPI 3: y=leaky(acc*rscale[row]); row-norm via 32-lane shfl; bf16 to Cb.
//   SCALEK (with TRANSA): A *= kscale[k] during staging.
// ---------------------------------------------------------------------------
template<bool TRANSA, bool SCALEK, int EPI>
__global__ __launch_bounds__(256, 2)
void gemm32(const float* __restrict__ A, int lda,
            const float* __restrict__ B, int ldb,
            float* __restrict__ C, unsigned short* __restrict__ Cb,
            int ksplit_len, int zstride,
            const float* __restrict__ kscale,
            const float* __restrict__ rscale,
            int ystA, int ystB, int ystC, int ystS)
{
    __shared__ float sA[32][68];
    __shared__ float sB[64][128];

    const int t  = threadIdx.x;
    const int ct = t & 31;
    const int rt = t >> 5;
    const int i0 = blockIdx.x * 32;
    const int side = blockIdx.y;
    const int kgbase = blockIdx.z * ksplit_len;

    A += (ptrdiff_t)side * ystA;
    B += (ptrdiff_t)side * ystB;
    if constexpr (EPI == 0)
        C += (ptrdiff_t)side * ystC + (size_t)blockIdx.z * (size_t)zstride;
    if constexpr (EPI == 3)
        Cb += (ptrdiff_t)side * ystC;
    if constexpr (SCALEK) kscale += (ptrdiff_t)side * ystS;
    if constexpr (EPI == 3) rscale += (ptrdiff_t)side * ystS;

    float4 acc[4];
    #pragma unroll
    for (int r = 0; r < 4; ++r) { acc[r].x = 0.f; acc[r].y = 0.f; acc[r].z = 0.f; acc[r].w = 0.f; }

    for (int k0 = 0; k0 < ksplit_len; k0 += 64) {
        const int kg = kgbase + k0;
        if (!TRANSA) {
            #pragma unroll
            for (int f = 0; f < 2; ++f) {
                const int row = (t >> 4) + 16 * f;
                const int kk4 = (t & 15) << 2;
                *reinterpret_cast<float4*>(&sA[row][kk4]) =
                    ldg4(&A[(size_t)(i0 + row) * lda + kg + kk4]);
            }
        } else {
            #pragma unroll
            for (int f = 0; f < 2; ++f) {
                const int kk = (t >> 3) + 32 * f;
                const int r4 = (t & 7) << 2;
                float4 v = ldg4(&A[(size_t)(kg + kk) * lda + i0 + r4]);
                if (SCALEK) {
                    const float s = kscale[kg + kk];
                    v.x *= s; v.y *= s; v.z *= s; v.w *= s;
                }
                sA[r4 + 0][kk] = v.x; sA[r4 + 1][kk] = v.y;
                sA[r4 + 2][kk] = v.z; sA[r4 + 3][kk] = v.w;
            }
        }
        #pragma unroll
        for (int f = 0; f < 8; ++f) {
            const int idx = f * 256 + t;
            const int kk  = idx >> 5;
            const int c4  = (idx & 31) << 2;
            *reinterpret_cast<float4*>(&sB[kk][c4]) =
                ldg4(&B[(size_t)(kg + kk) * ldb + c4]);
        }
        __syncthreads();
        #pragma unroll 4
        for (int kk = 0; kk < 64; kk += 4) {
            float4 a[4], b[4];
            #pragma unroll
            for (int r = 0; r < 4; ++r)
                a[r] = *reinterpret_cast<const float4*>(&sA[rt * 4 + r][kk]);
            #pragma unroll
            for (int q = 0; q < 4; ++q)
                b[q] = *reinterpret_cast<const float4*>(&sB[kk + q][ct * 4]);
            #pragma unroll
            for (int r = 0; r < 4; ++r) {
                acc[r].x += a[r].x * b[0].x; acc[r].y += a[r].x * b[0].y;
                acc[r].z += a[r].x * b[0].z; acc[r].w += a[r].x * b[0].w;
                acc[r].x += a[r].y * b[1].x; acc[r].y += a[r].y * b[1].y;
                acc[r].z += a[r].y * b[1].z; acc[r].w += a[r].y * b[1].w;
                acc[r].x += a[r].z * b[2].x; acc[r].y += a[r].z * b[2].y;
                acc[r].z += a[r].z * b[2].z; acc[r].w += a[r].z * b[2].w;
                acc[r].x += a[r].w * b[3].x; acc[r].y += a[r].w * b[3].y;
                acc[r].z += a[r].w * b[3].z; acc[r].w += a[r].w * b[3].w;
            }
        }
        __syncthreads();
    }

    #pragma unroll
    for (int r = 0; r < 4; ++r) {
        const int rg = i0 + rt * 4 + r;
        if constexpr (EPI == 3) {
            const float s = rscale[rg];
            float y0 = acc[r].x * s, y1 = acc[r].y * s,
                  y2 = acc[r].z * s, y3 = acc[r].w * s;
            y0 = (y0 >= 0.f) ? y0 : 0.01f * y0;
            y1 = (y1 >= 0.f) ? y1 : 0.01f * y1;
            y2 = (y2 >= 0.f) ? y2 : 0.01f * y2;
            y3 = (y3 >= 0.f) ? y3 : 0.01f * y3;
            float ss = y0 * y0 + y1 * y1 + y2 * y2 + y3 * y3;
            #pragma unroll
            for (int m = 16; m > 0; m >>= 1) ss += __shfl_xor(ss, m);
            const float invn = rsqrtf(ss);
            uint2 wv;
            wv.x = f2bf2(y0 * invn, y1 * invn);
            wv.y = f2bf2(y2 * invn, y3 * invn);
            *reinterpret_cast<uint2*>(&Cb[(size_t)rg * DD + ct * 4]) = wv;
        } else {
            *reinterpret_cast<float4*>(&C[(size_t)rg * DD + ct * 4]) = acc[r];
        }
    }
}

// ---------------------------------------------------------------------------
// K6: stacked reduce for the brackets: out[y][i] = sum_z part[y][z][i].
// ---------------------------------------------------------------------------
__global__ __launch_bounds__(256)
void reduce_mcmp(const float* __restrict__ part, float* __restrict__ out)
{
    const int y = blockIdx.y;
    const int i = blockIdx.x * 256 + threadIdx.x;   // 0..16383
    part += (size_t)y * 32 * 16384;
    out  += (size_t)y * 16384;
    float a = 0.f;
    #pragma unroll
    for (int z = 0; z < 32; ++z) a += part[(size_t)z * 16384 + i];
    out[i] = a;
}

// ---------------------------------------------------------------------------
extern "C" void kernel_launch(void* const* d_in, const int* in_sizes, int n_in,
                              void* d_out, int out_size, void* d_ws, size_t ws_size,
                              hipStream_t stream)
{
    const float* pre = (const float*)d_in[0];
    const float* cur = (const float*)d_in[1];
    const float* adj = (const float*)d_in[2];
    const float* W1  = (const float*)d_in[3];
    const float* W2  = (const float*)d_in[4];
    float* out = (float*)d_out;
    float* ws  = (float*)d_ws;

    const size_t M1 = (size_t)NN * DD;   // 1,048,576

    // ws layout (~96 MB of 1 GiB); d_out untouched until K8.
    float* cwpw2 = ws + 0 * M1;                               // [cw2; pw2] 2*M1
    float* c1    = ws + 2 * M1;                               // c1 then p1 (contig)
    unsigned short* c2n_b = (unsigned short*)(ws + 4 * M1);   // c2n then p2n (bf16)
    unsigned short* p2n_b = c2n_b + M1;
    unsigned short* cwT_b = (unsigned short*)(ws + 5 * M1);   // [128][8192] bf16
    unsigned short* pwT_b = cwT_b + M1;
    float* bparts = ws + 6 * M1;                              // [2][32][16384]
    float* mcmp   = ws + 7 * M1;                              // [mc; mp] 32768
    float* inc1   = mcmp + 32768;                             // inc1 then inp1
    float* kparts = ws + 8 * M1;                              // [16][M1]

    // K1: [pre|cur]@W1 -> pwT_b / cwT_b (transposed bf16, no fp32 store)
    gemm_w1t<<<dim3(512,1,1),256,0,stream>>>(pre, cur, W1, pwT_b, cwT_b);

    // K2: combined adj pass, split-K 8 per side (1024 blocks = 4/CU resident).
    //     z<8: pre1 partials (adj@cwT) -> kparts[0..7];
    //     z>=8: cur1 partials (adjT@pwT) -> kparts[8..15].
    mfma_tn<3><<<dim3(64,1,16),256,0,stream>>>(adj, NN, cwT_b, pwT_b, NN,
                                               kparts, DD, NN/8, (int)M1);

    // K3: stacked reduce+leaky+invnorm: y=0 -> c1/inc1, y=1 -> p1/inp1
    rln<<<dim3(NN,2,1),128,0,stream>>>(kparts, c1, inc1);

    // K4: [c1;p1]@W2 -> [cw2;pw2] (single M=16384 GEMM)
    gemm32<false,false,0><<<dim3(512,1,1),256,0,stream>>>(
        c1, DD, W2, DD, cwpw2, (unsigned short*)nullptr,
        DD, 0, nullptr, nullptr, 0,0,0,0);

    // K5: stacked brackets: side0 mc = (Dc^-1 c1)^T@cw2, side1 mp = (Dp^-1 p1)^T@pw2
    gemm32<true,true,0><<<dim3(4,2,32),256,0,stream>>>(
        c1, DD, cwpw2, DD, bparts, (unsigned short*)nullptr,
        256, 16384, inc1, nullptr,
        (int)M1, (int)M1, 32*16384, NN);

    // K6: stacked split-K reduce -> mcmp = [mc; mp]
    reduce_mcmp<<<dim3(64,2,1),256,0,stream>>>(bparts, mcmp);

    // K7: stacked fused tails (EPI3):
    //   side0: c2n = normrows(leaky(Dc^-1 c1 @ mp)) ; side1: p2n = ... (mc)
    gemm32<false,false,3><<<dim3(256,2,1),256,0,stream>>>(
        c1, DD, mcmp + 16384, DD, (float*)nullptr, c2n_b,
        DD, 0, nullptr, inc1,
        (int)M1, -16384, (int)M1, NN);

    // K8: adj2 = p2n @ c2n^T -> d_out (NT stores)
    mfma_tn<0><<<dim3(64,64,1),256,0,stream>>>(p2n_b, DD, c2n_b, c2n_b, DD,
                                               out, NN, DD, 0);
}